// Round 2
// baseline (8351.339 us; speedup 1.0000x reference)
//
#include <hip/hip_runtime.h>
#include <hip/hip_bf16.h>
#include <math.h>

#define BB 2
#define SS 2048
#define DD 1024
#define HH 16
#define DKK 64

typedef __bf16 bf16_t;
typedef __attribute__((ext_vector_type(8))) __bf16 bf16x8;
typedef __attribute__((ext_vector_type(4))) float f32x4;

// ---------------------------------------------------------------- cast kernels
__global__ void cast_f32_bf16(const float* __restrict__ in, bf16_t* __restrict__ out, int n) {
    int i = blockIdx.x * blockDim.x + threadIdx.x;
    int stride = gridDim.x * blockDim.x;
    for (; i < n; i += stride) out[i] = (bf16_t)in[i];
}

// split fp32 -> hi bf16 + lo bf16 (lo = round(x - hi)); hi+lo carries ~16 mantissa bits
__global__ void cast_split(const float* __restrict__ in, bf16_t* __restrict__ hi,
                           bf16_t* __restrict__ lo, int n) {
    int i = blockIdx.x * blockDim.x + threadIdx.x;
    int stride = gridDim.x * blockDim.x;
    for (; i < n; i += stride) {
        float v = in[i];
        bf16_t h = (bf16_t)v;
        hi[i] = h;
        lo[i] = (bf16_t)(v - (float)h);
    }
}

// ---------------------------------------------------------------- plain bf16 GEMM: C = A @ Bt^T + bias
// mode 0: out[M,N] fp32 row-major; mode 1: split-head layout [B,H,S,DK]
__global__ __launch_bounds__(256) void gemm_bt(const bf16_t* __restrict__ A,
                                               const bf16_t* __restrict__ Bt,
                                               const float* __restrict__ bias,
                                               float* __restrict__ out,
                                               int M, int N, int K, int mode) {
    __shared__ __align__(16) bf16_t As[64][40];
    __shared__ __align__(16) bf16_t Bs[64][40];

    const int tid  = threadIdx.x;
    const int wave = tid >> 6;
    const int lane = tid & 63;
    const int quad = lane >> 4;
    const int r    = lane & 15;
    const int row0 = blockIdx.y * 64;
    const int col0 = blockIdx.x * 64;

    f32x4 acc[4] = {{0.f,0.f,0.f,0.f},{0.f,0.f,0.f,0.f},{0.f,0.f,0.f,0.f},{0.f,0.f,0.f,0.f}};

    const int ar = tid >> 2;
    const int ac = (tid & 3) * 8;
    const bf16_t* Aptr = A  + (long)(row0 + ar) * K + ac;
    const bf16_t* Bptr = Bt + (long)(col0 + ar) * K + ac;

    for (int kb = 0; kb < K; kb += 32) {
        *(bf16x8*)&As[ar][ac] = *(const bf16x8*)(Aptr + kb);
        *(bf16x8*)&Bs[ar][ac] = *(const bf16x8*)(Bptr + kb);
        __syncthreads();

        bf16x8 a = *(const bf16x8*)&As[wave * 16 + r][quad * 8];
#pragma unroll
        for (int t = 0; t < 4; ++t) {
            bf16x8 b = *(const bf16x8*)&Bs[t * 16 + r][quad * 8];
            acc[t] = __builtin_amdgcn_mfma_f32_16x16x32_bf16(a, b, acc[t], 0, 0, 0);
        }
        __syncthreads();
    }

#pragma unroll
    for (int t = 0; t < 4; ++t) {
        int gcol = col0 + t * 16 + r;
        float bv = bias[gcol];
#pragma unroll
        for (int rr = 0; rr < 4; ++rr) {
            int grow = row0 + wave * 16 + quad * 4 + rr;
            float vv = acc[t][rr] + bv;
            if (mode == 0) {
                out[(long)grow * N + gcol] = vv;
            } else {
                int off = (((grow >> 11) * HH + (gcol >> 6)) * SS + (grow & (SS - 1))) * DKK + (gcol & 63);
                out[off] = vv;
            }
        }
    }
}

// ---------------------------------------------------------------- bf16x3 split-precision GEMM (for Q,K)
// C = (A_hi+A_lo) @ (B_hi+B_lo)^T + bias, dropping lo*lo. Output: split-head layout.
__global__ __launch_bounds__(256) void gemm_bt_x3(const bf16_t* __restrict__ Ah,
                                                  const bf16_t* __restrict__ Al,
                                                  const bf16_t* __restrict__ Bh,
                                                  const bf16_t* __restrict__ Bl,
                                                  const float* __restrict__ bias,
                                                  float* __restrict__ out,
                                                  int M, int N, int K) {
    __shared__ __align__(16) bf16_t Ash[64][40];
    __shared__ __align__(16) bf16_t Asl[64][40];
    __shared__ __align__(16) bf16_t Bsh[64][40];
    __shared__ __align__(16) bf16_t Bsl[64][40];

    const int tid  = threadIdx.x;
    const int wave = tid >> 6;
    const int lane = tid & 63;
    const int quad = lane >> 4;
    const int r    = lane & 15;
    const int row0 = blockIdx.y * 64;
    const int col0 = blockIdx.x * 64;

    f32x4 acc[4] = {{0.f,0.f,0.f,0.f},{0.f,0.f,0.f,0.f},{0.f,0.f,0.f,0.f},{0.f,0.f,0.f,0.f}};

    const int ar = tid >> 2;
    const int ac = (tid & 3) * 8;
    const long aoff = (long)(row0 + ar) * K + ac;
    const long boff = (long)(col0 + ar) * K + ac;

    for (int kb = 0; kb < K; kb += 32) {
        *(bf16x8*)&Ash[ar][ac] = *(const bf16x8*)(Ah + aoff + kb);
        *(bf16x8*)&Asl[ar][ac] = *(const bf16x8*)(Al + aoff + kb);
        *(bf16x8*)&Bsh[ar][ac] = *(const bf16x8*)(Bh + boff + kb);
        *(bf16x8*)&Bsl[ar][ac] = *(const bf16x8*)(Bl + boff + kb);
        __syncthreads();

        bf16x8 ah = *(const bf16x8*)&Ash[wave * 16 + r][quad * 8];
        bf16x8 al = *(const bf16x8*)&Asl[wave * 16 + r][quad * 8];
#pragma unroll
        for (int t = 0; t < 4; ++t) {
            bf16x8 bh = *(const bf16x8*)&Bsh[t * 16 + r][quad * 8];
            bf16x8 bl = *(const bf16x8*)&Bsl[t * 16 + r][quad * 8];
            acc[t] = __builtin_amdgcn_mfma_f32_16x16x32_bf16(ah, bh, acc[t], 0, 0, 0);
            acc[t] = __builtin_amdgcn_mfma_f32_16x16x32_bf16(ah, bl, acc[t], 0, 0, 0);
            acc[t] = __builtin_amdgcn_mfma_f32_16x16x32_bf16(al, bh, acc[t], 0, 0, 0);
        }
        __syncthreads();
    }

#pragma unroll
    for (int t = 0; t < 4; ++t) {
        int gcol = col0 + t * 16 + r;
        float bv = bias[gcol];
#pragma unroll
        for (int rr = 0; rr < 4; ++rr) {
            int grow = row0 + wave * 16 + quad * 4 + rr;
            float vv = acc[t][rr] + bv;
            int off = (((grow >> 11) * HH + (gcol >> 6)) * SS + (grow & (SS - 1))) * DKK + (gcol & 63);
            out[off] = vv;
        }
    }
}

// ---------------------------------------------------------------- attention (fp32, one wave per q row)
__global__ __launch_bounds__(256) void attn_fp32(const float* __restrict__ Q,
                                                 const float* __restrict__ Kk,
                                                 const float* __restrict__ V,
                                                 const int* __restrict__ mask,
                                                 bf16_t* __restrict__ ctx) {
    __shared__ float qs[4][64];
    __shared__ float ps[4][SS];

    const int tid  = threadIdx.x;
    const int wave = tid >> 6;
    const int lane = tid & 63;
    const int blk  = blockIdx.x;
    const int bh   = blk / (SS / 4);
    const int srow = (blk % (SS / 4)) * 4 + wave;
    const int b    = bh / HH;
    const int h    = bh % HH;

    qs[wave][lane] = Q[((long)bh * SS + srow) * DKK + lane];
    __syncthreads();

    const int* mrow = mask + b * SS;

#pragma unroll 1
    for (int c = 0; c < 32; ++c) {
        int kk = c * 64 + lane;
        const float* krow = Kk + ((long)bh * SS + kk) * DKK;
        float acc = 0.f;
#pragma unroll
        for (int d = 0; d < 64; d += 4) {
            float4 kv = *(const float4*)(krow + d);
            float4 qv = *(const float4*)(&qs[wave][d]);
            acc += qv.x * kv.x + qv.y * kv.y + qv.z * kv.z + qv.w * kv.w;
        }
        ps[wave][kk] = mrow[kk] ? acc * 8.0f : -3.402823466e38f;
    }

    float m = -3.402823466e38f;
#pragma unroll 1
    for (int c = 0; c < 32; ++c) m = fmaxf(m, ps[wave][c * 64 + lane]);
#pragma unroll
    for (int off = 1; off < 64; off <<= 1) m = fmaxf(m, __shfl_xor(m, off));

    float l = 0.f;
#pragma unroll 1
    for (int c = 0; c < 32; ++c) {
        int kk = c * 64 + lane;
        float e = __expf(ps[wave][kk] - m);
        ps[wave][kk] = e;
        l += e;
    }
#pragma unroll
    for (int off = 1; off < 64; off <<= 1) l += __shfl_xor(l, off);
    float inv = 1.0f / l;

    const float* vbase = V + (long)bh * SS * DKK + lane;
    float acc = 0.f;
#pragma unroll 1
    for (int k2 = 0; k2 < SS; k2 += 4) {
        float4 p4 = *(const float4*)&ps[wave][k2];
        acc += p4.x * vbase[(k2 + 0) * DKK];
        acc += p4.y * vbase[(k2 + 1) * DKK];
        acc += p4.z * vbase[(k2 + 2) * DKK];
        acc += p4.w * vbase[(k2 + 3) * DKK];
    }
    acc *= inv;

    ctx[((long)(b * SS + srow)) * DD + h * DKK + lane] = (bf16_t)acc;
}

// ---------------------------------------------------------------- launch
extern "C" void kernel_launch(void* const* d_in, const int* in_sizes, int n_in,
                              void* d_out, int out_size, void* d_ws, size_t ws_size,
                              hipStream_t stream) {
    const float* x  = (const float*)d_in[0];
    const int* mask = (const int*)d_in[1];
    const float* Wq = (const float*)d_in[2];
    const float* bq = (const float*)d_in[3];
    const float* Wk = (const float*)d_in[4];
    const float* bk = (const float*)d_in[5];
    const float* Wv = (const float*)d_in[6];
    const float* bv = (const float*)d_in[7];
    const float* Wo = (const float*)d_in[8];
    const float* bo = (const float*)d_in[9];
    float* out = (float*)d_out;

    const long NX = (long)BB * SS * DD;  // 4194304
    const long NW = (long)DD * DD;       // 1048576

    char* ws = (char*)d_ws;
    bf16_t* xh  = (bf16_t*)ws; ws += NX * 2;
    bf16_t* xl  = (bf16_t*)ws; ws += NX * 2;
    bf16_t* wqh = (bf16_t*)ws; ws += NW * 2;
    bf16_t* wql = (bf16_t*)ws; ws += NW * 2;
    bf16_t* wkh = (bf16_t*)ws; ws += NW * 2;
    bf16_t* wkl = (bf16_t*)ws; ws += NW * 2;
    bf16_t* wvb = (bf16_t*)ws; ws += NW * 2;
    bf16_t* wob = (bf16_t*)ws; ws += NW * 2;
    float*  q   = (float*)ws;  ws += NX * 4;
    float*  k   = (float*)ws;  ws += NX * 4;
    float*  v   = (float*)ws;  ws += NX * 4;
    bf16_t* ctx = (bf16_t*)ws; ws += NX * 2;

    cast_split<<<2048, 256, 0, stream>>>(x, xh, xl, (int)NX);
    cast_split<<<512, 256, 0, stream>>>(Wq, wqh, wql, (int)NW);
    cast_split<<<512, 256, 0, stream>>>(Wk, wkh, wkl, (int)NW);
    cast_f32_bf16<<<512, 256, 0, stream>>>(Wv, wvb, (int)NW);
    cast_f32_bf16<<<512, 256, 0, stream>>>(Wo, wob, (int)NW);

    dim3 pgrid(DD / 64, (BB * SS) / 64);  // (16, 64)
    gemm_bt_x3<<<pgrid, 256, 0, stream>>>(xh, xl, wqh, wql, bq, q, BB * SS, DD, DD);
    gemm_bt_x3<<<pgrid, 256, 0, stream>>>(xh, xl, wkh, wkl, bk, k, BB * SS, DD, DD);
    gemm_bt<<<pgrid, 256, 0, stream>>>(xh, wvb, bv, v, BB * SS, DD, DD, 1);

    attn_fp32<<<BB * HH * (SS / 4), 256, 0, stream>>>(q, k, v, mask, ctx);

    gemm_bt<<<pgrid, 256, 0, stream>>>(ctx, wob, bo, out, BB * SS, DD, DD, 0);
}

// Round 5
// 411.886 us; speedup vs baseline: 20.2758x; 20.2758x over previous
//
#include <hip/hip_runtime.h>
#include <hip/hip_bf16.h>
#include <math.h>

#define BB 2
#define SS 2048
#define DD 1024
#define HH 16
#define DKK 64

typedef __bf16 bf16_t;
typedef __attribute__((ext_vector_type(8))) __bf16 bf16x8;
typedef __attribute__((ext_vector_type(4))) __bf16 bf16x4;
typedef __attribute__((ext_vector_type(4))) float f32x4;

// ---------------------------------------------------------------- cast kernels
__global__ void cast_f32_bf16(const float* __restrict__ in, bf16_t* __restrict__ out, int n) {
    int i = blockIdx.x * blockDim.x + threadIdx.x;
    int stride = gridDim.x * blockDim.x;
    for (; i < n; i += stride) out[i] = (bf16_t)in[i];
}

// split fp32 -> hi bf16 + lo bf16 (hi+lo carries ~16 mantissa bits)
__global__ void cast_split(const float* __restrict__ in, bf16_t* __restrict__ hi,
                           bf16_t* __restrict__ lo, int n) {
    int i = blockIdx.x * blockDim.x + threadIdx.x;
    int stride = gridDim.x * blockDim.x;
    for (; i < n; i += stride) {
        float v = in[i];
        bf16_t h = (bf16_t)v;
        hi[i] = h;
        lo[i] = (bf16_t)(v - (float)h);
    }
}

// ---------------------------------------------------------------- plain bf16 GEMM: out[M,N] fp32 (O-projection)
__global__ __launch_bounds__(256) void gemm_bt(const bf16_t* __restrict__ A,
                                               const bf16_t* __restrict__ Bt,
                                               const float* __restrict__ bias,
                                               float* __restrict__ out,
                                               int M, int N, int K) {
    __shared__ __align__(16) bf16_t As[64][40];
    __shared__ __align__(16) bf16_t Bs[64][40];

    const int tid  = threadIdx.x;
    const int wave = tid >> 6;
    const int lane = tid & 63;
    const int quad = lane >> 4;
    const int r    = lane & 15;
    const int row0 = blockIdx.y * 64;
    const int col0 = blockIdx.x * 64;

    f32x4 acc[4] = {{0.f,0.f,0.f,0.f},{0.f,0.f,0.f,0.f},{0.f,0.f,0.f,0.f},{0.f,0.f,0.f,0.f}};

    const int ar = tid >> 2;
    const int ac = (tid & 3) * 8;
    const bf16_t* Aptr = A  + (long)(row0 + ar) * K + ac;
    const bf16_t* Bptr = Bt + (long)(col0 + ar) * K + ac;

    for (int kb = 0; kb < K; kb += 32) {
        *(bf16x8*)&As[ar][ac] = *(const bf16x8*)(Aptr + kb);
        *(bf16x8*)&Bs[ar][ac] = *(const bf16x8*)(Bptr + kb);
        __syncthreads();

        bf16x8 a = *(const bf16x8*)&As[wave * 16 + r][quad * 8];
#pragma unroll
        for (int t = 0; t < 4; ++t) {
            bf16x8 b = *(const bf16x8*)&Bs[t * 16 + r][quad * 8];
            acc[t] = __builtin_amdgcn_mfma_f32_16x16x32_bf16(a, b, acc[t], 0, 0, 0);
        }
        __syncthreads();
    }

#pragma unroll
    for (int t = 0; t < 4; ++t) {
        int gcol = col0 + t * 16 + r;
        float bv = bias[gcol];
#pragma unroll
        for (int rr = 0; rr < 4; ++rr) {
            int grow = row0 + wave * 16 + quad * 4 + rr;
            out[(long)grow * N + gcol] = acc[t][rr] + bv;
        }
    }
}

// ---------------------------------------------------------------- V-projection GEMM: bf16 out in V^T layout [B,H,DK,S]
__global__ __launch_bounds__(256) void gemm_bt_vt(const bf16_t* __restrict__ A,
                                                  const bf16_t* __restrict__ Bt,
                                                  const float* __restrict__ bias,
                                                  bf16_t* __restrict__ out,
                                                  int M, int N, int K) {
    __shared__ __align__(16) bf16_t As[64][40];
    __shared__ __align__(16) bf16_t Bs[64][40];

    const int tid  = threadIdx.x;
    const int wave = tid >> 6;
    const int lane = tid & 63;
    const int quad = lane >> 4;
    const int r    = lane & 15;
    const int row0 = blockIdx.y * 64;
    const int col0 = blockIdx.x * 64;

    f32x4 acc[4] = {{0.f,0.f,0.f,0.f},{0.f,0.f,0.f,0.f},{0.f,0.f,0.f,0.f},{0.f,0.f,0.f,0.f}};

    const int ar = tid >> 2;
    const int ac = (tid & 3) * 8;
    const bf16_t* Aptr = A  + (long)(row0 + ar) * K + ac;
    const bf16_t* Bptr = Bt + (long)(col0 + ar) * K + ac;

    for (int kb = 0; kb < K; kb += 32) {
        *(bf16x8*)&As[ar][ac] = *(const bf16x8*)(Aptr + kb);
        *(bf16x8*)&Bs[ar][ac] = *(const bf16x8*)(Bptr + kb);
        __syncthreads();

        bf16x8 a = *(const bf16x8*)&As[wave * 16 + r][quad * 8];
#pragma unroll
        for (int t = 0; t < 4; ++t) {
            bf16x8 b = *(const bf16x8*)&Bs[t * 16 + r][quad * 8];
            acc[t] = __builtin_amdgcn_mfma_f32_16x16x32_bf16(a, b, acc[t], 0, 0, 0);
        }
        __syncthreads();
    }

    // grow = b*S + s ; gcol = h*DK + dk  ->  out[((b*H+h)*DK + dk)*S + s], 4 consecutive s per lane
    const int grow0 = row0 + wave * 16 + quad * 4;
    const int bq = grow0 >> 11;
    const int s0 = grow0 & (SS - 1);
#pragma unroll
    for (int t = 0; t < 4; ++t) {
        int gcol = col0 + t * 16 + r;
        float bv = bias[gcol];
        int hq = gcol >> 6, dk = gcol & 63;
        bf16x4 pk;
#pragma unroll
        for (int rr = 0; rr < 4; ++rr) pk[rr] = (bf16_t)(acc[t][rr] + bv);
        *(bf16x4*)(out + ((long)(bq * HH + hq) * DKK + dk) * SS + s0) = pk;
    }
}

// ---------------------------------------------------------------- bf16x3 split GEMM (Q,K): hi/lo bf16 out, split-head [B,H,S,DK]
__global__ __launch_bounds__(256) void gemm_bt_x3(const bf16_t* __restrict__ Ah,
                                                  const bf16_t* __restrict__ Al,
                                                  const bf16_t* __restrict__ Bh,
                                                  const bf16_t* __restrict__ Bl,
                                                  const float* __restrict__ bias,
                                                  bf16_t* __restrict__ oh,
                                                  bf16_t* __restrict__ ol,
                                                  int M, int N, int K) {
    __shared__ __align__(16) bf16_t Ash[64][40];
    __shared__ __align__(16) bf16_t Asl[64][40];
    __shared__ __align__(16) bf16_t Bsh[64][40];
    __shared__ __align__(16) bf16_t Bsl[64][40];

    const int tid  = threadIdx.x;
    const int wave = tid >> 6;
    const int lane = tid & 63;
    const int quad = lane >> 4;
    const int r    = lane & 15;
    const int row0 = blockIdx.y * 64;
    const int col0 = blockIdx.x * 64;

    f32x4 acc[4] = {{0.f,0.f,0.f,0.f},{0.f,0.f,0.f,0.f},{0.f,0.f,0.f,0.f},{0.f,0.f,0.f,0.f}};

    const int ar = tid >> 2;
    const int ac = (tid & 3) * 8;
    const long aoff = (long)(row0 + ar) * K + ac;
    const long boff = (long)(col0 + ar) * K + ac;

    for (int kb = 0; kb < K; kb += 32) {
        *(bf16x8*)&Ash[ar][ac] = *(const bf16x8*)(Ah + aoff + kb);
        *(bf16x8*)&Asl[ar][ac] = *(const bf16x8*)(Al + aoff + kb);
        *(bf16x8*)&Bsh[ar][ac] = *(const bf16x8*)(Bh + boff + kb);
        *(bf16x8*)&Bsl[ar][ac] = *(const bf16x8*)(Bl + boff + kb);
        __syncthreads();

        bf16x8 ah = *(const bf16x8*)&Ash[wave * 16 + r][quad * 8];
        bf16x8 al = *(const bf16x8*)&Asl[wave * 16 + r][quad * 8];
#pragma unroll
        for (int t = 0; t < 4; ++t) {
            bf16x8 bh = *(const bf16x8*)&Bsh[t * 16 + r][quad * 8];
            bf16x8 bl = *(const bf16x8*)&Bsl[t * 16 + r][quad * 8];
            acc[t] = __builtin_amdgcn_mfma_f32_16x16x32_bf16(ah, bh, acc[t], 0, 0, 0);
            acc[t] = __builtin_amdgcn_mfma_f32_16x16x32_bf16(ah, bl, acc[t], 0, 0, 0);
            acc[t] = __builtin_amdgcn_mfma_f32_16x16x32_bf16(al, bh, acc[t], 0, 0, 0);
        }
        __syncthreads();
    }

#pragma unroll
    for (int t = 0; t < 4; ++t) {
        int gcol = col0 + t * 16 + r;
        float bv = bias[gcol];
        int hq = gcol >> 6, dk = gcol & 63;
#pragma unroll
        for (int rr = 0; rr < 4; ++rr) {
            int grow = row0 + wave * 16 + quad * 4 + rr;
            float vv = acc[t][rr] + bv;
            bf16_t hi = (bf16_t)vv;
            int off = (((grow >> 11) * HH + hq) * SS + (grow & (SS - 1))) * DKK + dk;
            oh[off] = hi;
            ol[off] = (bf16_t)(vv - (float)hi);
        }
    }
}

// ---------------------------------------------------------------- MFMA flash attention
// block = 4 waves; wave owns 16 q rows; block streams 64-key tiles of one (b,h).
// seq_len passed as runtime arg so the kt loop CANNOT be fully unrolled.
__global__ __launch_bounds__(256) void attn_mfma(const bf16_t* __restrict__ Qhp,
                                                 const bf16_t* __restrict__ Qlp,
                                                 const bf16_t* __restrict__ Khp,
                                                 const bf16_t* __restrict__ Klp,
                                                 const bf16_t* __restrict__ Vtp,
                                                 const int* __restrict__ mask,
                                                 bf16_t* __restrict__ ctx,
                                                 int seq_len) {
    __shared__ __align__(16) bf16_t Ksh[64][72];
    __shared__ __align__(16) bf16_t Ksl[64][72];
    __shared__ __align__(16) bf16_t Vsh[64][72];
    __shared__ __align__(16) bf16_t Psh[4][16][72];

    const int tid  = threadIdx.x;
    const int wv   = tid >> 6;
    const int lane = tid & 63;
    const int quad = lane >> 4;
    const int l15  = lane & 15;
    const int bh   = blockIdx.y;
    const int b    = bh >> 4;
    const int h    = bh & 15;
    const int q0   = blockIdx.x * 64 + wv * 16;

    const long kb = (long)bh * SS * DKK;  // also == bh*DKK*SS for Vt

    // Q fragments (A-layout): A[m=lane&15][k=quad*8+j], d-tiles {0,32}
    bf16x8 qfh[2], qfl[2];
    {
        const bf16_t* ph = Qhp + kb + (long)(q0 + l15) * DKK + quad * 8;
        const bf16_t* pl = Qlp + kb + (long)(q0 + l15) * DKK + quad * 8;
        qfh[0] = *(const bf16x8*)ph;  qfh[1] = *(const bf16x8*)(ph + 32);
        qfl[0] = *(const bf16x8*)pl;  qfl[1] = *(const bf16x8*)(pl + 32);
    }

    f32x4 o[4];
    float m[4], l[4];
#pragma unroll
    for (int r = 0; r < 4; ++r) {
        o[r] = (f32x4){0.f, 0.f, 0.f, 0.f};
        m[r] = -1e30f;
        l[r] = 0.f;
    }

    const int* mrow = mask + b * SS;
    const int sr = tid >> 3;         // 0..31 staging row
    const int sc = (tid & 7) * 8;    // staging col (8 bf16)

#pragma unroll 1
    for (int kt = 0; kt < seq_len; kt += 64) {
#pragma unroll
        for (int p = 0; p < 2; ++p) {
            int rr = sr + p * 32;
            *(bf16x8*)&Ksh[rr][sc] = *(const bf16x8*)(Khp + kb + (long)(kt + rr) * DKK + sc);
            *(bf16x8*)&Ksl[rr][sc] = *(const bf16x8*)(Klp + kb + (long)(kt + rr) * DKK + sc);
            *(bf16x8*)&Vsh[rr][sc] = *(const bf16x8*)(Vtp + kb + (long)rr * SS + kt + sc);
        }
        __syncthreads();

        // ---- scores S = Q K^T (split x3), D[m=qrow(quad*4+reg)][n=key(lane&15)]
        f32x4 s[4];
#pragma unroll
        for (int nt = 0; nt < 4; ++nt) s[nt] = (f32x4){0.f, 0.f, 0.f, 0.f};
#pragma unroll
        for (int nt = 0; nt < 4; ++nt) {
#pragma unroll
            for (int dt = 0; dt < 2; ++dt) {
                bf16x8 kh  = *(const bf16x8*)&Ksh[nt * 16 + l15][dt * 32 + quad * 8];
                bf16x8 klo = *(const bf16x8*)&Ksl[nt * 16 + l15][dt * 32 + quad * 8];
                s[nt] = __builtin_amdgcn_mfma_f32_16x16x32_bf16(qfh[dt], kh,  s[nt], 0, 0, 0);
                s[nt] = __builtin_amdgcn_mfma_f32_16x16x32_bf16(qfh[dt], klo, s[nt], 0, 0, 0);
                s[nt] = __builtin_amdgcn_mfma_f32_16x16x32_bf16(qfl[dt], kh,  s[nt], 0, 0, 0);
            }
        }

        // ---- scale (x8 = 1/dk^-0.5) + key-padding mask
#pragma unroll
        for (int nt = 0; nt < 4; ++nt) {
            int keep = mrow[kt + nt * 16 + l15];
#pragma unroll
            for (int r = 0; r < 4; ++r)
                s[nt][r] = keep ? s[nt][r] * 8.0f : -1e30f;
        }

        // ---- tile row max (reduce over 4 n-tiles + 16 lanes of the quad)
        float tm[4];
#pragma unroll
        for (int r = 0; r < 4; ++r)
            tm[r] = fmaxf(fmaxf(s[0][r], s[1][r]), fmaxf(s[2][r], s[3][r]));
#pragma unroll
        for (int off = 1; off < 16; off <<= 1) {
#pragma unroll
            for (int r = 0; r < 4; ++r) tm[r] = fmaxf(tm[r], __shfl_xor(tm[r], off));
        }

        // ---- online softmax update
        float alpha[4], ts[4];
#pragma unroll
        for (int r = 0; r < 4; ++r) {
            float mn = fmaxf(m[r], tm[r]);
            alpha[r] = __expf(m[r] - mn);
            m[r] = mn;
            ts[r] = 0.f;
        }
#pragma unroll
        for (int nt = 0; nt < 4; ++nt) {
#pragma unroll
            for (int r = 0; r < 4; ++r) {
                float p = __expf(s[nt][r] - m[r]);
                ts[r] += p;
                Psh[wv][quad * 4 + r][nt * 16 + l15] = (bf16_t)p;
            }
        }
#pragma unroll
        for (int off = 1; off < 16; off <<= 1) {
#pragma unroll
            for (int r = 0; r < 4; ++r) ts[r] += __shfl_xor(ts[r], off);
        }
#pragma unroll
        for (int r = 0; r < 4; ++r) l[r] = l[r] * alpha[r] + ts[r];

        // ---- rescale O
#pragma unroll
        for (int t = 0; t < 4; ++t)
#pragma unroll
            for (int r = 0; r < 4; ++r) o[t][r] *= alpha[r];

        // ---- PV: O[q][d] += P[q][k] V[k][d]; A=P (LDS round-trip), B=V^T rows
#pragma unroll
        for (int kk = 0; kk < 2; ++kk) {
            bf16x8 pf = *(const bf16x8*)&Psh[wv][l15][kk * 32 + quad * 8];
#pragma unroll
            for (int t = 0; t < 4; ++t) {
                bf16x8 vf = *(const bf16x8*)&Vsh[t * 16 + l15][kk * 32 + quad * 8];
                o[t] = __builtin_amdgcn_mfma_f32_16x16x32_bf16(pf, vf, o[t], 0, 0, 0);
            }
        }
        __syncthreads();
    }

    // ---- epilogue: normalize, write ctx[token][h*64+d] bf16
    float inv[4];
#pragma unroll
    for (int r = 0; r < 4; ++r) inv[r] = 1.0f / l[r];
#pragma unroll
    for (int t = 0; t < 4; ++t) {
        int d = t * 16 + l15;
#pragma unroll
        for (int r = 0; r < 4; ++r) {
            int tok = b * SS + q0 + quad * 4 + r;
            ctx[(long)tok * DD + h * DKK + d] = (bf16_t)(o[t][r] * inv[r]);
        }
    }
}

// ---------------------------------------------------------------- launch
extern "C" void kernel_launch(void* const* d_in, const int* in_sizes, int n_in,
                              void* d_out, int out_size, void* d_ws, size_t ws_size,
                              hipStream_t stream) {
    const float* x  = (const float*)d_in[0];
    const int* mask = (const int*)d_in[1];
    const float* Wq = (const float*)d_in[2];
    const float* bq = (const float*)d_in[3];
    const float* Wk = (const float*)d_in[4];
    const float* bk = (const float*)d_in[5];
    const float* Wv = (const float*)d_in[6];
    const float* bv = (const float*)d_in[7];
    const float* Wo = (const float*)d_in[8];
    const float* bo = (const float*)d_in[9];
    float* out = (float*)d_out;

    const long NX = (long)BB * SS * DD;  // 4194304
    const long NW = (long)DD * DD;       // 1048576

    char* ws = (char*)d_ws;
    bf16_t* xh  = (bf16_t*)ws; ws += NX * 2;
    bf16_t* xl  = (bf16_t*)ws; ws += NX * 2;
    bf16_t* wqh = (bf16_t*)ws; ws += NW * 2;
    bf16_t* wql = (bf16_t*)ws; ws += NW * 2;
    bf16_t* wkh = (bf16_t*)ws; ws += NW * 2;
    bf16_t* wkl = (bf16_t*)ws; ws += NW * 2;
    bf16_t* wvb = (bf16_t*)ws; ws += NW * 2;
    bf16_t* wob = (bf16_t*)ws; ws += NW * 2;
    bf16_t* qh  = (bf16_t*)ws; ws += NX * 2;
    bf16_t* ql  = (bf16_t*)ws; ws += NX * 2;
    bf16_t* kh  = (bf16_t*)ws; ws += NX * 2;
    bf16_t* kl  = (bf16_t*)ws; ws += NX * 2;
    bf16_t* vt  = (bf16_t*)ws; ws += NX * 2;
    bf16_t* ctx = (bf16_t*)ws; ws += NX * 2;

    cast_split<<<2048, 256, 0, stream>>>(x, xh, xl, (int)NX);
    cast_split<<<512, 256, 0, stream>>>(Wq, wqh, wql, (int)NW);
    cast_split<<<512, 256, 0, stream>>>(Wk, wkh, wkl, (int)NW);
    cast_f32_bf16<<<512, 256, 0, stream>>>(Wv, wvb, (int)NW);
    cast_f32_bf16<<<512, 256, 0, stream>>>(Wo, wob, (int)NW);

    dim3 pgrid(DD / 64, (BB * SS) / 64);  // (16, 64)
    gemm_bt_x3<<<pgrid, 256, 0, stream>>>(xh, xl, wqh, wql, bq, qh, ql, BB * SS, DD, DD);
    gemm_bt_x3<<<pgrid, 256, 0, stream>>>(xh, xl, wkh, wkl, bk, kh, kl, BB * SS, DD, DD);
    gemm_bt_vt<<<pgrid, 256, 0, stream>>>(xh, wvb, bv, vt, BB * SS, DD, DD);

    dim3 agrid(SS / 64, BB * HH);  // (32, 32)
    attn_mfma<<<agrid, 256, 0, stream>>>(qh, ql, kh, kl, vt, mask, ctx, SS);

    gemm_bt<<<pgrid, 256, 0, stream>>>(ctx, wob, bo, out, BB * SS, DD, DD);
}

// Round 7
// 379.298 us; speedup vs baseline: 22.0179x; 1.0859x over previous
//
#include <hip/hip_runtime.h>
#include <hip/hip_bf16.h>
#include <math.h>

#define BB 2
#define SS 2048
#define DD 1024
#define HH 16
#define DKK 64

typedef __bf16 bf16_t;
typedef __attribute__((ext_vector_type(8))) __bf16 bf16x8;
typedef __attribute__((ext_vector_type(4))) __bf16 bf16x4;
typedef __attribute__((ext_vector_type(4))) float f32x4;

// async global->LDS, 16B per lane; lds base must be wave-uniform (lane*16 implicit)
#define GLD_LDS(gp, lp) __builtin_amdgcn_global_load_lds( \
    (const __attribute__((address_space(1))) void*)(gp),  \
    (__attribute__((address_space(3))) void*)(lp), 16, 0, 0)

// ---------------------------------------------------------------- cast kernels
__global__ void cast_f32_bf16(const float* __restrict__ in, bf16_t* __restrict__ out, int n) {
    int i = blockIdx.x * blockDim.x + threadIdx.x;
    int stride = gridDim.x * blockDim.x;
    for (; i < n; i += stride) out[i] = (bf16_t)in[i];
}

__global__ void cast_split(const float* __restrict__ in, bf16_t* __restrict__ hi,
                           bf16_t* __restrict__ lo, int n) {
    int i = blockIdx.x * blockDim.x + threadIdx.x;
    int stride = gridDim.x * blockDim.x;
    for (; i < n; i += stride) {
        float v = in[i];
        bf16_t h = (bf16_t)v;
        hi[i] = h;
        lo[i] = (bf16_t)(v - (float)h);
    }
}

// ---------------------------------------------------------------- m97-style GEMM
// C = A @ Bt^T (+ lo-cross terms if X3) + bias.  A:[M,K] bf16, Bt:[N,K] bf16.
// Tile 64x128, BK=32, 4 waves (2x2), per-wave 32x64 (2x4 16x16 accs).
// MODE 0: fp32 out[M,N]; MODE 1: hi/lo bf16 split-head [B,H,S,DK]; MODE 2: bf16 V^T [B,H,DK,S]
template<bool X3, int MODE>
__global__ __launch_bounds__(256) void gemm2(const bf16_t* __restrict__ Ah,
                                             const bf16_t* __restrict__ Al,
                                             const bf16_t* __restrict__ Bh,
                                             const bf16_t* __restrict__ Bl,
                                             const float* __restrict__ bias,
                                             float* __restrict__ outf,
                                             bf16_t* __restrict__ oh,
                                             bf16_t* __restrict__ ol,
                                             int N, int K) {
    constexpr int ANE = 64 * 32;   // 2048 elems
    constexpr int BNE = 128 * 32;  // 4096 elems
    __shared__ __align__(16) bf16_t lds[X3 ? 2 * (ANE + BNE) : (ANE + BNE)];
    bf16_t* Ash = lds;
    bf16_t* Bsh = lds + ANE;

    const int tid  = threadIdx.x;
    const int wv   = tid >> 6;
    const int lane = tid & 63;
    const int quad = lane >> 4;
    const int l15  = lane & 15;
    const int wr   = wv >> 1;      // 0,1 : m-half
    const int wc   = wv & 1;       // 0,1 : n-half
    const int row0 = blockIdx.y * 64;
    const int col0 = blockIdx.x * 128;

    f32x4 acc[2][4] = {};

    // staging: lane -> (row = lane>>2, col = (lane&3)*8) within a 16-row chunk
    const int srow = lane >> 2;
    const int scol = (lane & 3) * 8;
    const bf16_t* gA  = Ah + (long)(row0 + wv * 16 + srow) * K + scol;       // A chunk wv
    const bf16_t* gB0 = Bh + (long)(col0 + wv * 16 + srow) * K + scol;       // B chunk wv
    const bf16_t* gB1 = Bh + (long)(col0 + (wv + 4) * 16 + srow) * K + scol; // B chunk wv+4
    bf16_t* lA  = Ash + wv * 512;
    bf16_t* lB0 = Bsh + wv * 512;
    bf16_t* lB1 = Bsh + (wv + 4) * 512;

    const bf16_t *gAl = nullptr, *gBl0 = nullptr, *gBl1 = nullptr;
    bf16_t *lAl = nullptr, *lBl0 = nullptr, *lBl1 = nullptr;
    if constexpr (X3) {
        gAl  = Al + (long)(row0 + wv * 16 + srow) * K + scol;
        gBl0 = Bl + (long)(col0 + wv * 16 + srow) * K + scol;
        gBl1 = Bl + (long)(col0 + (wv + 4) * 16 + srow) * K + scol;
        lAl  = lds + ANE + BNE + wv * 512;
        lBl0 = lds + 2 * ANE + BNE + wv * 512;
        lBl1 = lds + 2 * ANE + BNE + (wv + 4) * 512;
    }

#pragma unroll 1
    for (int kb = 0; kb < K; kb += 32) {
        GLD_LDS(gA + kb, lA);
        GLD_LDS(gB0 + kb, lB0);
        GLD_LDS(gB1 + kb, lB1);
        if constexpr (X3) {
            GLD_LDS(gAl + kb, lAl);
            GLD_LDS(gBl0 + kb, lBl0);
            GLD_LDS(gBl1 + kb, lBl1);
        }
        __syncthreads();

        bf16x8 af[2], alf[2];
#pragma unroll
        for (int mt = 0; mt < 2; ++mt) {
            af[mt] = *(const bf16x8*)&Ash[(wr * 32 + mt * 16 + l15) * 32 + quad * 8];
            if constexpr (X3)
                alf[mt] = *(const bf16x8*)&lds[ANE + BNE + (wr * 32 + mt * 16 + l15) * 32 + quad * 8];
        }
#pragma unroll
        for (int nt = 0; nt < 4; ++nt) {
            bf16x8 bh = *(const bf16x8*)&Bsh[(wc * 64 + nt * 16 + l15) * 32 + quad * 8];
            if constexpr (X3) {
                bf16x8 bl = *(const bf16x8*)&lds[2 * ANE + BNE + (wc * 64 + nt * 16 + l15) * 32 + quad * 8];
#pragma unroll
                for (int mt = 0; mt < 2; ++mt) {
                    acc[mt][nt] = __builtin_amdgcn_mfma_f32_16x16x32_bf16(af[mt], bh, acc[mt][nt], 0, 0, 0);
                    acc[mt][nt] = __builtin_amdgcn_mfma_f32_16x16x32_bf16(af[mt], bl, acc[mt][nt], 0, 0, 0);
                    acc[mt][nt] = __builtin_amdgcn_mfma_f32_16x16x32_bf16(alf[mt], bh, acc[mt][nt], 0, 0, 0);
                }
            } else {
#pragma unroll
                for (int mt = 0; mt < 2; ++mt)
                    acc[mt][nt] = __builtin_amdgcn_mfma_f32_16x16x32_bf16(af[mt], bh, acc[mt][nt], 0, 0, 0);
            }
        }
        __syncthreads();
    }

#pragma unroll
    for (int mt = 0; mt < 2; ++mt) {
#pragma unroll
        for (int nt = 0; nt < 4; ++nt) {
            const int gcol  = col0 + wc * 64 + nt * 16 + l15;
            const float bv  = bias[gcol];
            const int grow0 = row0 + wr * 32 + mt * 16 + quad * 4;
            if constexpr (MODE == 0) {
#pragma unroll
                for (int r = 0; r < 4; ++r)
                    outf[(long)(grow0 + r) * N + gcol] = acc[mt][nt][r] + bv;
            } else if constexpr (MODE == 1) {
                const int hq = gcol >> 6, dk = gcol & 63;
#pragma unroll
                for (int r = 0; r < 4; ++r) {
                    int grow = grow0 + r;
                    float vv = acc[mt][nt][r] + bv;
                    bf16_t hi = (bf16_t)vv;
                    long off = (((long)(grow >> 11) * HH + hq) * SS + (grow & (SS - 1))) * DKK + dk;
                    oh[off] = hi;
                    ol[off] = (bf16_t)(vv - (float)hi);
                }
            } else {
                const int hq = gcol >> 6, dk = gcol & 63;
                const int bq2 = grow0 >> 11;
                const int s0  = grow0 & (SS - 1);
                bf16x4 pk;
#pragma unroll
                for (int r = 0; r < 4; ++r) pk[r] = (bf16_t)(acc[mt][nt][r] + bv);
                *(bf16x4*)(oh + ((long)(bq2 * HH + hq) * DKK + dk) * SS + s0) = pk;
            }
        }
    }
}

// ---------------------------------------------------------------- MFMA flash attention (unchanged from R5)
__global__ __launch_bounds__(256) void attn_mfma(const bf16_t* __restrict__ Qhp,
                                                 const bf16_t* __restrict__ Qlp,
                                                 const bf16_t* __restrict__ Khp,
                                                 const bf16_t* __restrict__ Klp,
                                                 const bf16_t* __restrict__ Vtp,
                                                 const int* __restrict__ mask,
                                                 bf16_t* __restrict__ ctx,
                                                 int seq_len) {
    __shared__ __align__(16) bf16_t Ksh[64][72];
    __shared__ __align__(16) bf16_t Ksl[64][72];
    __shared__ __align__(16) bf16_t Vsh[64][72];
    __shared__ __align__(16) bf16_t Psh[4][16][72];

    const int tid  = threadIdx.x;
    const int wv   = tid >> 6;
    const int lane = tid & 63;
    const int quad = lane >> 4;
    const int l15  = lane & 15;
    const int bh   = blockIdx.y;
    const int b    = bh >> 4;
    const int h    = bh & 15;
    const int q0   = blockIdx.x * 64 + wv * 16;

    const long kb = (long)bh * SS * DKK;

    bf16x8 qfh[2], qfl[2];
    {
        const bf16_t* ph = Qhp + kb + (long)(q0 + l15) * DKK + quad * 8;
        const bf16_t* pl = Qlp + kb + (long)(q0 + l15) * DKK + quad * 8;
        qfh[0] = *(const bf16x8*)ph;  qfh[1] = *(const bf16x8*)(ph + 32);
        qfl[0] = *(const bf16x8*)pl;  qfl[1] = *(const bf16x8*)(pl + 32);
    }

    f32x4 o[4];
    float m[4], l[4];
#pragma unroll
    for (int r = 0; r < 4; ++r) {
        o[r] = (f32x4){0.f, 0.f, 0.f, 0.f};
        m[r] = -1e30f;
        l[r] = 0.f;
    }

    const int* mrow = mask + b * SS;
    const int sr = tid >> 3;
    const int sc = (tid & 7) * 8;

#pragma unroll 1
    for (int kt = 0; kt < seq_len; kt += 64) {
#pragma unroll
        for (int p = 0; p < 2; ++p) {
            int rr = sr + p * 32;
            *(bf16x8*)&Ksh[rr][sc] = *(const bf16x8*)(Khp + kb + (long)(kt + rr) * DKK + sc);
            *(bf16x8*)&Ksl[rr][sc] = *(const bf16x8*)(Klp + kb + (long)(kt + rr) * DKK + sc);
            *(bf16x8*)&Vsh[rr][sc] = *(const bf16x8*)(Vtp + kb + (long)rr * SS + kt + sc);
        }
        __syncthreads();

        f32x4 s[4];
#pragma unroll
        for (int nt = 0; nt < 4; ++nt) s[nt] = (f32x4){0.f, 0.f, 0.f, 0.f};
#pragma unroll
        for (int nt = 0; nt < 4; ++nt) {
#pragma unroll
            for (int dt = 0; dt < 2; ++dt) {
                bf16x8 kh  = *(const bf16x8*)&Ksh[nt * 16 + l15][dt * 32 + quad * 8];
                bf16x8 klo = *(const bf16x8*)&Ksl[nt * 16 + l15][dt * 32 + quad * 8];
                s[nt] = __builtin_amdgcn_mfma_f32_16x16x32_bf16(qfh[dt], kh,  s[nt], 0, 0, 0);
                s[nt] = __builtin_amdgcn_mfma_f32_16x16x32_bf16(qfh[dt], klo, s[nt], 0, 0, 0);
                s[nt] = __builtin_amdgcn_mfma_f32_16x16x32_bf16(qfl[dt], kh,  s[nt], 0, 0, 0);
            }
        }

#pragma unroll
        for (int nt = 0; nt < 4; ++nt) {
            int keep = mrow[kt + nt * 16 + l15];
#pragma unroll
            for (int r = 0; r < 4; ++r)
                s[nt][r] = keep ? s[nt][r] * 8.0f : -1e30f;
        }

        float tm[4];
#pragma unroll
        for (int r = 0; r < 4; ++r)
            tm[r] = fmaxf(fmaxf(s[0][r], s[1][r]), fmaxf(s[2][r], s[3][r]));
#pragma unroll
        for (int off = 1; off < 16; off <<= 1) {
#pragma unroll
            for (int r = 0; r < 4; ++r) tm[r] = fmaxf(tm[r], __shfl_xor(tm[r], off));
        }

        float alpha[4], ts[4];
#pragma unroll
        for (int r = 0; r < 4; ++r) {
            float mn = fmaxf(m[r], tm[r]);
            alpha[r] = __expf(m[r] - mn);
            m[r] = mn;
            ts[r] = 0.f;
        }
#pragma unroll
        for (int nt = 0; nt < 4; ++nt) {
#pragma unroll
            for (int r = 0; r < 4; ++r) {
                float p = __expf(s[nt][r] - m[r]);
                ts[r] += p;
                Psh[wv][quad * 4 + r][nt * 16 + l15] = (bf16_t)p;
            }
        }
#pragma unroll
        for (int off = 1; off < 16; off <<= 1) {
#pragma unroll
            for (int r = 0; r < 4; ++r) ts[r] += __shfl_xor(ts[r], off);
        }
#pragma unroll
        for (int r = 0; r < 4; ++r) l[r] = l[r] * alpha[r] + ts[r];

#pragma unroll
        for (int t = 0; t < 4; ++t)
#pragma unroll
            for (int r = 0; r < 4; ++r) o[t][r] *= alpha[r];

#pragma unroll
        for (int kk = 0; kk < 2; ++kk) {
            bf16x8 pf = *(const bf16x8*)&Psh[wv][l15][kk * 32 + quad * 8];
#pragma unroll
            for (int t = 0; t < 4; ++t) {
                bf16x8 vf = *(const bf16x8*)&Vsh[t * 16 + l15][kk * 32 + quad * 8];
                o[t] = __builtin_amdgcn_mfma_f32_16x16x32_bf16(pf, vf, o[t], 0, 0, 0);
            }
        }
        __syncthreads();
    }

    float inv[4];
#pragma unroll
    for (int r = 0; r < 4; ++r) inv[r] = 1.0f / l[r];
#pragma unroll
    for (int t = 0; t < 4; ++t) {
        int d = t * 16 + l15;
#pragma unroll
        for (int r = 0; r < 4; ++r) {
            int tok = b * SS + q0 + quad * 4 + r;
            ctx[(long)tok * DD + h * DKK + d] = (bf16_t)(o[t][r] * inv[r]);
        }
    }
}

// ---------------------------------------------------------------- launch
extern "C" void kernel_launch(void* const* d_in, const int* in_sizes, int n_in,
                              void* d_out, int out_size, void* d_ws, size_t ws_size,
                              hipStream_t stream) {
    const float* x  = (const float*)d_in[0];
    const int* mask = (const int*)d_in[1];
    const float* Wq = (const float*)d_in[2];
    const float* bq = (const float*)d_in[3];
    const float* Wk = (const float*)d_in[4];
    const float* bk = (const float*)d_in[5];
    const float* Wv = (const float*)d_in[6];
    const float* bv = (const float*)d_in[7];
    const float* Wo = (const float*)d_in[8];
    const float* bo = (const float*)d_in[9];
    float* out = (float*)d_out;

    const long NX = (long)BB * SS * DD;  // 4194304
    const long NW = (long)DD * DD;       // 1048576

    char* ws = (char*)d_ws;
    bf16_t* xh  = (bf16_t*)ws; ws += NX * 2;
    bf16_t* xl  = (bf16_t*)ws; ws += NX * 2;
    bf16_t* wqh = (bf16_t*)ws; ws += NW * 2;
    bf16_t* wql = (bf16_t*)ws; ws += NW * 2;
    bf16_t* wkh = (bf16_t*)ws; ws += NW * 2;
    bf16_t* wkl = (bf16_t*)ws; ws += NW * 2;
    bf16_t* wvb = (bf16_t*)ws; ws += NW * 2;
    bf16_t* wob = (bf16_t*)ws; ws += NW * 2;
    bf16_t* qh  = (bf16_t*)ws; ws += NX * 2;
    bf16_t* ql  = (bf16_t*)ws; ws += NX * 2;
    bf16_t* kh  = (bf16_t*)ws; ws += NX * 2;
    bf16_t* kl  = (bf16_t*)ws; ws += NX * 2;
    bf16_t* vt  = (bf16_t*)ws; ws += NX * 2;
    bf16_t* ctx = (bf16_t*)ws; ws += NX * 2;

    cast_split<<<2048, 256, 0, stream>>>(x, xh, xl, (int)NX);
    cast_split<<<512, 256, 0, stream>>>(Wq, wqh, wql, (int)NW);
    cast_split<<<512, 256, 0, stream>>>(Wk, wkh, wkl, (int)NW);
    cast_f32_bf16<<<512, 256, 0, stream>>>(Wv, wvb, (int)NW);
    cast_f32_bf16<<<512, 256, 0, stream>>>(Wo, wob, (int)NW);

    dim3 g2(DD / 128, (BB * SS) / 64);  // (8, 64) = 512 blocks
    gemm2<true, 1><<<g2, 256, 0, stream>>>(xh, xl, wqh, wql, bq, nullptr, qh, ql, DD, DD);
    gemm2<true, 1><<<g2, 256, 0, stream>>>(xh, xl, wkh, wkl, bk, nullptr, kh, kl, DD, DD);
    gemm2<false, 2><<<g2, 256, 0, stream>>>(xh, nullptr, wvb, nullptr, bv, nullptr, vt, nullptr, DD, DD);

    dim3 agrid(SS / 64, BB * HH);  // (32, 32)
    attn_mfma<<<agrid, 256, 0, stream>>>(qh, ql, kh, kl, vt, mask, ctx, SS);

    gemm2<false, 0><<<g2, 256, 0, stream>>>(ctx, nullptr, wob, nullptr, bo, out, nullptr, nullptr, DD, DD);
}

// Round 8
// 358.905 us; speedup vs baseline: 23.2689x; 1.0568x over previous
//
#include <hip/hip_runtime.h>
#include <hip/hip_bf16.h>
#include <math.h>

#define BB 2
#define SS 2048
#define DD 1024
#define HH 16
#define DKK 64

typedef __bf16 bf16_t;
typedef __attribute__((ext_vector_type(8))) __bf16 bf16x8;
typedef __attribute__((ext_vector_type(4))) __bf16 bf16x4;
typedef __attribute__((ext_vector_type(4))) float f32x4;

// async global->LDS, 16B per lane; lds base must be wave-uniform (lane*16 implicit)
#define GLD_LDS(gp, lp) __builtin_amdgcn_global_load_lds( \
    (const __attribute__((address_space(1))) void*)(gp),  \
    (__attribute__((address_space(3))) void*)(lp), 16, 0, 0)

// ---------------------------------------------------------------- cast kernels
__global__ void cast_f32_bf16(const float* __restrict__ in, bf16_t* __restrict__ out, int n) {
    int i = blockIdx.x * blockDim.x + threadIdx.x;
    int stride = gridDim.x * blockDim.x;
    for (; i < n; i += stride) out[i] = (bf16_t)in[i];
}

__global__ void cast_split(const float* __restrict__ in, bf16_t* __restrict__ hi,
                           bf16_t* __restrict__ lo, int n) {
    int i = blockIdx.x * blockDim.x + threadIdx.x;
    int stride = gridDim.x * blockDim.x;
    for (; i < n; i += stride) {
        float v = in[i];
        bf16_t h = (bf16_t)v;
        hi[i] = h;
        lo[i] = (bf16_t)(v - (float)h);
    }
}

// ---------------------------------------------------------------- fused Q+K x3 GEMM
// A:[4096,1024] hi/lo bf16; B:[2048,1024] hi/lo bf16 (rows 0..1023 = Wq, 1024..2047 = Wk).
// Tile 128x128, BK=32, 4 waves 2x2, per-wave 64x64 (4x4 16x16 accs).
// Output: hi/lo bf16 split-head [B,H,S,DK] into q or k buffers by column.
__global__ __launch_bounds__(256) void gemm_qk(const bf16_t* __restrict__ Ah,
                                               const bf16_t* __restrict__ Al,
                                               const bf16_t* __restrict__ Bh,
                                               const bf16_t* __restrict__ Bl,
                                               const float* __restrict__ bq,
                                               const float* __restrict__ bk,
                                               bf16_t* __restrict__ qh_o,
                                               bf16_t* __restrict__ ql_o,
                                               bf16_t* __restrict__ kh_o,
                                               bf16_t* __restrict__ kl_o,
                                               int K) {
    __shared__ __align__(16) bf16_t lds[16384];  // 4 chunks of 128x32
    bf16_t* sAh = lds;
    bf16_t* sAl = lds + 4096;
    bf16_t* sBh = lds + 8192;
    bf16_t* sBl = lds + 12288;

    const int tid  = threadIdx.x;
    const int wv   = tid >> 6;
    const int lane = tid & 63;
    const int quad = lane >> 4;
    const int l15  = lane & 15;
    const int wr   = wv >> 1;
    const int wc   = wv & 1;
    const int row0 = blockIdx.y * 128;
    const int col0 = blockIdx.x * 128;

    f32x4 acc[4][4] = {};

    // staging: thread t -> row (t>>2)+64p, col (t&3)*8 ; LDS addr = p*2048 + wv*512 + lane*8
    const int srow = tid >> 2;
    const int scol = (tid & 3) * 8;
    const long aoff = (long)(row0 + srow) * K + scol;
    const long boff = (long)(col0 + srow) * K + scol;

#pragma unroll 1
    for (int kb = 0; kb < K; kb += 32) {
#pragma unroll
        for (int p = 0; p < 2; ++p) {
            const long go = (long)p * 64 * K + kb;
            const int lo = p * 2048 + wv * 512;
            GLD_LDS(Ah + aoff + go, sAh + lo);
            GLD_LDS(Al + aoff + go, sAl + lo);
            GLD_LDS(Bh + boff + go, sBh + lo);
            GLD_LDS(Bl + boff + go, sBl + lo);
        }
        __syncthreads();

        bf16x8 afh[4], afl[4];
#pragma unroll
        for (int mt = 0; mt < 4; ++mt) {
            const int ar = wr * 64 + mt * 16 + l15;
            afh[mt] = *(const bf16x8*)&sAh[ar * 32 + quad * 8];
            afl[mt] = *(const bf16x8*)&sAl[ar * 32 + quad * 8];
        }
#pragma unroll
        for (int nt = 0; nt < 4; ++nt) {
            const int br = wc * 64 + nt * 16 + l15;
            bf16x8 bh = *(const bf16x8*)&sBh[br * 32 + quad * 8];
            bf16x8 bl = *(const bf16x8*)&sBl[br * 32 + quad * 8];
#pragma unroll
            for (int mt = 0; mt < 4; ++mt) {
                acc[mt][nt] = __builtin_amdgcn_mfma_f32_16x16x32_bf16(afh[mt], bh, acc[mt][nt], 0, 0, 0);
                acc[mt][nt] = __builtin_amdgcn_mfma_f32_16x16x32_bf16(afh[mt], bl, acc[mt][nt], 0, 0, 0);
                acc[mt][nt] = __builtin_amdgcn_mfma_f32_16x16x32_bf16(afl[mt], bh, acc[mt][nt], 0, 0, 0);
            }
        }
        __syncthreads();
    }

    // epilogue: col0 in [0,2048); >=1024 -> K projection (block-uniform)
    const bool isK = (col0 >= 1024);
    const float* bias = isK ? bk : bq;
    bf16_t* ohp = isK ? kh_o : qh_o;
    bf16_t* olp = isK ? kl_o : ql_o;
#pragma unroll
    for (int nt = 0; nt < 4; ++nt) {
        const int gcol = (col0 & 1023) + wc * 64 + nt * 16 + l15;  // within [0,1024)
        const float bv = bias[gcol];
        const int hq = gcol >> 6, dk = gcol & 63;
#pragma unroll
        for (int mt = 0; mt < 4; ++mt) {
            const int grow0 = row0 + wr * 64 + mt * 16 + quad * 4;
#pragma unroll
            for (int r = 0; r < 4; ++r) {
                int grow = grow0 + r;
                float vv = acc[mt][nt][r] + bv;
                bf16_t hi = (bf16_t)vv;
                long off = (((long)(grow >> 11) * HH + hq) * SS + (grow & (SS - 1))) * DKK + dk;
                ohp[off] = hi;
                olp[off] = (bf16_t)(vv - (float)hi);
            }
        }
    }
}

// ---------------------------------------------------------------- 64x128 GEMM (V and O projections)
// MODE 0: fp32 out[M,N]; MODE 2: bf16 V^T [B,H,DK,S]
template<int MODE>
__global__ __launch_bounds__(256) void gemm2(const bf16_t* __restrict__ Ah,
                                             const bf16_t* __restrict__ Bh,
                                             const float* __restrict__ bias,
                                             float* __restrict__ outf,
                                             bf16_t* __restrict__ oh,
                                             int N, int K) {
    constexpr int ANE = 64 * 32;
    constexpr int BNE = 128 * 32;
    __shared__ __align__(16) bf16_t lds[ANE + BNE];
    bf16_t* Ash = lds;
    bf16_t* Bsh = lds + ANE;

    const int tid  = threadIdx.x;
    const int wv   = tid >> 6;
    const int lane = tid & 63;
    const int quad = lane >> 4;
    const int l15  = lane & 15;
    const int wr   = wv >> 1;
    const int wc   = wv & 1;
    const int row0 = blockIdx.y * 64;
    const int col0 = blockIdx.x * 128;

    f32x4 acc[2][4] = {};

    const int srow = lane >> 2;
    const int scol = (lane & 3) * 8;
    const bf16_t* gA  = Ah + (long)(row0 + wv * 16 + srow) * K + scol;
    const bf16_t* gB0 = Bh + (long)(col0 + wv * 16 + srow) * K + scol;
    const bf16_t* gB1 = Bh + (long)(col0 + (wv + 4) * 16 + srow) * K + scol;
    bf16_t* lA  = Ash + wv * 512;
    bf16_t* lB0 = Bsh + wv * 512;
    bf16_t* lB1 = Bsh + (wv + 4) * 512;

#pragma unroll 1
    for (int kb = 0; kb < K; kb += 32) {
        GLD_LDS(gA + kb, lA);
        GLD_LDS(gB0 + kb, lB0);
        GLD_LDS(gB1 + kb, lB1);
        __syncthreads();

        bf16x8 af[2];
#pragma unroll
        for (int mt = 0; mt < 2; ++mt)
            af[mt] = *(const bf16x8*)&Ash[(wr * 32 + mt * 16 + l15) * 32 + quad * 8];
#pragma unroll
        for (int nt = 0; nt < 4; ++nt) {
            bf16x8 bh = *(const bf16x8*)&Bsh[(wc * 64 + nt * 16 + l15) * 32 + quad * 8];
#pragma unroll
            for (int mt = 0; mt < 2; ++mt)
                acc[mt][nt] = __builtin_amdgcn_mfma_f32_16x16x32_bf16(af[mt], bh, acc[mt][nt], 0, 0, 0);
        }
        __syncthreads();
    }

#pragma unroll
    for (int mt = 0; mt < 2; ++mt) {
#pragma unroll
        for (int nt = 0; nt < 4; ++nt) {
            const int gcol  = col0 + wc * 64 + nt * 16 + l15;
            const float bv  = bias[gcol];
            const int grow0 = row0 + wr * 32 + mt * 16 + quad * 4;
            if constexpr (MODE == 0) {
#pragma unroll
                for (int r = 0; r < 4; ++r)
                    outf[(long)(grow0 + r) * N + gcol] = acc[mt][nt][r] + bv;
            } else {
                const int hq = gcol >> 6, dk = gcol & 63;
                const int bq2 = grow0 >> 11;
                const int s0  = grow0 & (SS - 1);
                bf16x4 pk;
#pragma unroll
                for (int r = 0; r < 4; ++r) pk[r] = (bf16_t)(acc[mt][nt][r] + bv);
                *(bf16x4*)(oh + ((long)(bq2 * HH + hq) * DKK + dk) * SS + s0) = pk;
            }
        }
    }
}

// ---------------------------------------------------------------- MFMA flash attention (unchanged)
__global__ __launch_bounds__(256) void attn_mfma(const bf16_t* __restrict__ Qhp,
                                                 const bf16_t* __restrict__ Qlp,
                                                 const bf16_t* __restrict__ Khp,
                                                 const bf16_t* __restrict__ Klp,
                                                 const bf16_t* __restrict__ Vtp,
                                                 const int* __restrict__ mask,
                                                 bf16_t* __restrict__ ctx,
                                                 int seq_len) {
    __shared__ __align__(16) bf16_t Ksh[64][72];
    __shared__ __align__(16) bf16_t Ksl[64][72];
    __shared__ __align__(16) bf16_t Vsh[64][72];
    __shared__ __align__(16) bf16_t Psh[4][16][72];

    const int tid  = threadIdx.x;
    const int wv   = tid >> 6;
    const int lane = tid & 63;
    const int quad = lane >> 4;
    const int l15  = lane & 15;
    const int bh   = blockIdx.y;
    const int b    = bh >> 4;
    const int h    = bh & 15;
    const int q0   = blockIdx.x * 64 + wv * 16;

    const long kb = (long)bh * SS * DKK;

    bf16x8 qfh[2], qfl[2];
    {
        const bf16_t* ph = Qhp + kb + (long)(q0 + l15) * DKK + quad * 8;
        const bf16_t* pl = Qlp + kb + (long)(q0 + l15) * DKK + quad * 8;
        qfh[0] = *(const bf16x8*)ph;  qfh[1] = *(const bf16x8*)(ph + 32);
        qfl[0] = *(const bf16x8*)pl;  qfl[1] = *(const bf16x8*)(pl + 32);
    }

    f32x4 o[4];
    float m[4], l[4];
#pragma unroll
    for (int r = 0; r < 4; ++r) {
        o[r] = (f32x4){0.f, 0.f, 0.f, 0.f};
        m[r] = -1e30f;
        l[r] = 0.f;
    }

    const int* mrow = mask + b * SS;
    const int sr = tid >> 3;
    const int sc = (tid & 7) * 8;

#pragma unroll 1
    for (int kt = 0; kt < seq_len; kt += 64) {
#pragma unroll
        for (int p = 0; p < 2; ++p) {
            int rr = sr + p * 32;
            *(bf16x8*)&Ksh[rr][sc] = *(const bf16x8*)(Khp + kb + (long)(kt + rr) * DKK + sc);
            *(bf16x8*)&Ksl[rr][sc] = *(const bf16x8*)(Klp + kb + (long)(kt + rr) * DKK + sc);
            *(bf16x8*)&Vsh[rr][sc] = *(const bf16x8*)(Vtp + kb + (long)rr * SS + kt + sc);
        }
        __syncthreads();

        f32x4 s[4];
#pragma unroll
        for (int nt = 0; nt < 4; ++nt) s[nt] = (f32x4){0.f, 0.f, 0.f, 0.f};
#pragma unroll
        for (int nt = 0; nt < 4; ++nt) {
#pragma unroll
            for (int dt = 0; dt < 2; ++dt) {
                bf16x8 kh  = *(const bf16x8*)&Ksh[nt * 16 + l15][dt * 32 + quad * 8];
                bf16x8 klo = *(const bf16x8*)&Ksl[nt * 16 + l15][dt * 32 + quad * 8];
                s[nt] = __builtin_amdgcn_mfma_f32_16x16x32_bf16(qfh[dt], kh,  s[nt], 0, 0, 0);
                s[nt] = __builtin_amdgcn_mfma_f32_16x16x32_bf16(qfh[dt], klo, s[nt], 0, 0, 0);
                s[nt] = __builtin_amdgcn_mfma_f32_16x16x32_bf16(qfl[dt], kh,  s[nt], 0, 0, 0);
            }
        }

#pragma unroll
        for (int nt = 0; nt < 4; ++nt) {
            int keep = mrow[kt + nt * 16 + l15];
#pragma unroll
            for (int r = 0; r < 4; ++r)
                s[nt][r] = keep ? s[nt][r] * 8.0f : -1e30f;
        }

        float tm[4];
#pragma unroll
        for (int r = 0; r < 4; ++r)
            tm[r] = fmaxf(fmaxf(s[0][r], s[1][r]), fmaxf(s[2][r], s[3][r]));
#pragma unroll
        for (int off = 1; off < 16; off <<= 1) {
#pragma unroll
            for (int r = 0; r < 4; ++r) tm[r] = fmaxf(tm[r], __shfl_xor(tm[r], off));
        }

        float alpha[4], ts[4];
#pragma unroll
        for (int r = 0; r < 4; ++r) {
            float mn = fmaxf(m[r], tm[r]);
            alpha[r] = __expf(m[r] - mn);
            m[r] = mn;
            ts[r] = 0.f;
        }
#pragma unroll
        for (int nt = 0; nt < 4; ++nt) {
#pragma unroll
            for (int r = 0; r < 4; ++r) {
                float p = __expf(s[nt][r] - m[r]);
                ts[r] += p;
                Psh[wv][quad * 4 + r][nt * 16 + l15] = (bf16_t)p;
            }
        }
#pragma unroll
        for (int off = 1; off < 16; off <<= 1) {
#pragma unroll
            for (int r = 0; r < 4; ++r) ts[r] += __shfl_xor(ts[r], off);
        }
#pragma unroll
        for (int r = 0; r < 4; ++r) l[r] = l[r] * alpha[r] + ts[r];

#pragma unroll
        for (int t = 0; t < 4; ++t)
#pragma unroll
            for (int r = 0; r < 4; ++r) o[t][r] *= alpha[r];

#pragma unroll
        for (int kk = 0; kk < 2; ++kk) {
            bf16x8 pf = *(const bf16x8*)&Psh[wv][l15][kk * 32 + quad * 8];
#pragma unroll
            for (int t = 0; t < 4; ++t) {
                bf16x8 vf = *(const bf16x8*)&Vsh[t * 16 + l15][kk * 32 + quad * 8];
                o[t] = __builtin_amdgcn_mfma_f32_16x16x32_bf16(pf, vf, o[t], 0, 0, 0);
            }
        }
        __syncthreads();
    }

    float inv[4];
#pragma unroll
    for (int r = 0; r < 4; ++r) inv[r] = 1.0f / l[r];
#pragma unroll
    for (int t = 0; t < 4; ++t) {
        int d = t * 16 + l15;
#pragma unroll
        for (int r = 0; r < 4; ++r) {
            int tok = b * SS + q0 + quad * 4 + r;
            ctx[(long)tok * DD + h * DKK + d] = (bf16_t)(o[t][r] * inv[r]);
        }
    }
}

// ---------------------------------------------------------------- launch
extern "C" void kernel_launch(void* const* d_in, const int* in_sizes, int n_in,
                              void* d_out, int out_size, void* d_ws, size_t ws_size,
                              hipStream_t stream) {
    const float* x  = (const float*)d_in[0];
    const int* mask = (const int*)d_in[1];
    const float* Wq = (const float*)d_in[2];
    const float* bq = (const float*)d_in[3];
    const float* Wk = (const float*)d_in[4];
    const float* bk = (const float*)d_in[5];
    const float* Wv = (const float*)d_in[6];
    const float* bv = (const float*)d_in[7];
    const float* Wo = (const float*)d_in[8];
    const float* bo = (const float*)d_in[9];
    float* out = (float*)d_out;

    const long NX = (long)BB * SS * DD;  // 4194304
    const long NW = (long)DD * DD;       // 1048576

    char* ws = (char*)d_ws;
    bf16_t* xh   = (bf16_t*)ws; ws += NX * 2;
    bf16_t* xl   = (bf16_t*)ws; ws += NX * 2;
    bf16_t* wqkh = (bf16_t*)ws; ws += 2 * NW * 2;  // fused [Wq;Wk] hi
    bf16_t* wqkl = (bf16_t*)ws; ws += 2 * NW * 2;  // fused [Wq;Wk] lo
    bf16_t* wvb  = (bf16_t*)ws; ws += NW * 2;
    bf16_t* wob  = (bf16_t*)ws; ws += NW * 2;
    bf16_t* qh   = (bf16_t*)ws; ws += NX * 2;
    bf16_t* ql   = (bf16_t*)ws; ws += NX * 2;
    bf16_t* kh   = (bf16_t*)ws; ws += NX * 2;
    bf16_t* kl   = (bf16_t*)ws; ws += NX * 2;
    bf16_t* vt   = (bf16_t*)ws; ws += NX * 2;
    bf16_t* ctx  = (bf16_t*)ws; ws += NX * 2;

    cast_split<<<2048, 256, 0, stream>>>(x, xh, xl, (int)NX);
    cast_split<<<512, 256, 0, stream>>>(Wq, wqkh, wqkl, (int)NW);
    cast_split<<<512, 256, 0, stream>>>(Wk, wqkh + NW, wqkl + NW, (int)NW);
    cast_f32_bf16<<<512, 256, 0, stream>>>(Wv, wvb, (int)NW);
    cast_f32_bf16<<<512, 256, 0, stream>>>(Wo, wob, (int)NW);

    dim3 gqk(2 * DD / 128, (BB * SS) / 128);  // (16, 32) = 512 blocks
    gemm_qk<<<gqk, 256, 0, stream>>>(xh, xl, wqkh, wqkl, bq, bk, qh, ql, kh, kl, DD);

    dim3 g2(DD / 128, (BB * SS) / 64);  // (8, 64) = 512 blocks
    gemm2<2><<<g2, 256, 0, stream>>>(xh, wvb, bv, nullptr, vt, DD, DD);

    dim3 agrid(SS / 64, BB * HH);  // (32, 32)
    attn_mfma<<<agrid, 256, 0, stream>>>(qh, ql, kh, kl, vt, mask, ctx, SS);

    gemm2<0><<<g2, 256, 0, stream>>>(ctx, wob, bo, out, nullptr, DD, DD);
}

// Round 9
// 314.050 us; speedup vs baseline: 26.5924x; 1.1428x over previous
//
#include <hip/hip_runtime.h>
#include <hip/hip_bf16.h>
#include <math.h>

#define BB 2
#define SS 2048
#define DD 1024
#define HH 16
#define DKK 64

typedef __bf16 bf16_t;
typedef _Float16 f16_t;
typedef __attribute__((ext_vector_type(8))) __bf16 bf16x8;
typedef __attribute__((ext_vector_type(4))) __bf16 bf16x4;
typedef __attribute__((ext_vector_type(8))) _Float16 f16x8;
typedef __attribute__((ext_vector_type(4))) _Float16 f16x4;
typedef __attribute__((ext_vector_type(4))) float f32x4;

// async global->LDS, 16B per lane; lds base must be wave-uniform (lane*16 implicit)
#define GLD_LDS(gp, lp) __builtin_amdgcn_global_load_lds( \
    (const __attribute__((address_space(1))) void*)(gp),  \
    (__attribute__((address_space(3))) void*)(lp), 16, 0, 0)

// ---------------------------------------------------------------- cast kernels
__global__ void cast_f32_bf16(const float* __restrict__ in, bf16_t* __restrict__ out, int n) {
    int i = blockIdx.x * blockDim.x + threadIdx.x;
    int stride = gridDim.x * blockDim.x;
    for (; i < n; i += stride) out[i] = (bf16_t)in[i];
}

__global__ void cast_split(const float* __restrict__ in, bf16_t* __restrict__ hi,
                           bf16_t* __restrict__ lo, int n) {
    int i = blockIdx.x * blockDim.x + threadIdx.x;
    int stride = gridDim.x * blockDim.x;
    for (; i < n; i += stride) {
        float v = in[i];
        bf16_t h = (bf16_t)v;
        hi[i] = h;
        lo[i] = (bf16_t)(v - (float)h);
    }
}

// ---------------------------------------------------------------- fused Q+K x3 GEMM -> fp16 split-head outputs
// A:[4096,1024] hi/lo bf16; B:[2048,1024] hi/lo bf16 (rows 0..1023 = Wq, 1024..2047 = Wk).
// Tile 128x128, BK=32, 4 waves 2x2, per-wave 64x64 (4x4 16x16 accs).
__global__ __launch_bounds__(256) void gemm_qk(const bf16_t* __restrict__ Ah,
                                               const bf16_t* __restrict__ Al,
                                               const bf16_t* __restrict__ Bh,
                                               const bf16_t* __restrict__ Bl,
                                               const float* __restrict__ bq,
                                               const float* __restrict__ bk,
                                               f16_t* __restrict__ q_o,
                                               f16_t* __restrict__ k_o,
                                               int K) {
    __shared__ __align__(16) bf16_t lds[16384];  // 4 chunks of 128x32
    bf16_t* sAh = lds;
    bf16_t* sAl = lds + 4096;
    bf16_t* sBh = lds + 8192;
    bf16_t* sBl = lds + 12288;

    const int tid  = threadIdx.x;
    const int wv   = tid >> 6;
    const int lane = tid & 63;
    const int quad = lane >> 4;
    const int l15  = lane & 15;
    const int wr   = wv >> 1;
    const int wc   = wv & 1;
    const int row0 = blockIdx.y * 128;
    const int col0 = blockIdx.x * 128;

    f32x4 acc[4][4] = {};

    const int srow = tid >> 2;
    const int scol = (tid & 3) * 8;
    const long aoff = (long)(row0 + srow) * K + scol;
    const long boff = (long)(col0 + srow) * K + scol;

#pragma unroll 1
    for (int kb = 0; kb < K; kb += 32) {
#pragma unroll
        for (int p = 0; p < 2; ++p) {
            const long go = (long)p * 64 * K + kb;
            const int lo = p * 2048 + wv * 512;
            GLD_LDS(Ah + aoff + go, sAh + lo);
            GLD_LDS(Al + aoff + go, sAl + lo);
            GLD_LDS(Bh + boff + go, sBh + lo);
            GLD_LDS(Bl + boff + go, sBl + lo);
        }
        __syncthreads();

        bf16x8 afh[4], afl[4];
#pragma unroll
        for (int mt = 0; mt < 4; ++mt) {
            const int ar = wr * 64 + mt * 16 + l15;
            afh[mt] = *(const bf16x8*)&sAh[ar * 32 + quad * 8];
            afl[mt] = *(const bf16x8*)&sAl[ar * 32 + quad * 8];
        }
#pragma unroll
        for (int nt = 0; nt < 4; ++nt) {
            const int br = wc * 64 + nt * 16 + l15;
            bf16x8 bh = *(const bf16x8*)&sBh[br * 32 + quad * 8];
            bf16x8 bl = *(const bf16x8*)&sBl[br * 32 + quad * 8];
#pragma unroll
            for (int mt = 0; mt < 4; ++mt) {
                acc[mt][nt] = __builtin_amdgcn_mfma_f32_16x16x32_bf16(afh[mt], bh, acc[mt][nt], 0, 0, 0);
                acc[mt][nt] = __builtin_amdgcn_mfma_f32_16x16x32_bf16(afh[mt], bl, acc[mt][nt], 0, 0, 0);
                acc[mt][nt] = __builtin_amdgcn_mfma_f32_16x16x32_bf16(afl[mt], bh, acc[mt][nt], 0, 0, 0);
            }
        }
        __syncthreads();
    }

    const bool isK = (col0 >= 1024);
    const float* bias = isK ? bk : bq;
    f16_t* op = isK ? k_o : q_o;
#pragma unroll
    for (int nt = 0; nt < 4; ++nt) {
        const int gcol = (col0 & 1023) + wc * 64 + nt * 16 + l15;
        const float bv = bias[gcol];
        const int hq = gcol >> 6, dk = gcol & 63;
#pragma unroll
        for (int mt = 0; mt < 4; ++mt) {
            const int grow0 = row0 + wr * 64 + mt * 16 + quad * 4;
#pragma unroll
            for (int r = 0; r < 4; ++r) {
                int grow = grow0 + r;
                float vv = acc[mt][nt][r] + bv;
                long off = (((long)(grow >> 11) * HH + hq) * SS + (grow & (SS - 1))) * DKK + dk;
                op[off] = (f16_t)vv;
            }
        }
    }
}

// ---------------------------------------------------------------- 64x128 GEMM (V and O projections)
// MODE 0: fp32 out[M,N]; MODE 2: fp16 V^T [B,H,DK,S]
template<int MODE>
__global__ __launch_bounds__(256) void gemm2(const bf16_t* __restrict__ Ah,
                                             const bf16_t* __restrict__ Bh,
                                             const float* __restrict__ bias,
                                             float* __restrict__ outf,
                                             f16_t* __restrict__ oh,
                                             int N, int K) {
    constexpr int ANE = 64 * 32;
    constexpr int BNE = 128 * 32;
    __shared__ __align__(16) bf16_t lds[ANE + BNE];
    bf16_t* Ash = lds;
    bf16_t* Bsh = lds + ANE;

    const int tid  = threadIdx.x;
    const int wv   = tid >> 6;
    const int lane = tid & 63;
    const int quad = lane >> 4;
    const int l15  = lane & 15;
    const int wr   = wv >> 1;
    const int wc   = wv & 1;
    const int row0 = blockIdx.y * 64;
    const int col0 = blockIdx.x * 128;

    f32x4 acc[2][4] = {};

    const int srow = lane >> 2;
    const int scol = (lane & 3) * 8;
    const bf16_t* gA  = Ah + (long)(row0 + wv * 16 + srow) * K + scol;
    const bf16_t* gB0 = Bh + (long)(col0 + wv * 16 + srow) * K + scol;
    const bf16_t* gB1 = Bh + (long)(col0 + (wv + 4) * 16 + srow) * K + scol;
    bf16_t* lA  = Ash + wv * 512;
    bf16_t* lB0 = Bsh + wv * 512;
    bf16_t* lB1 = Bsh + (wv + 4) * 512;

#pragma unroll 1
    for (int kb = 0; kb < K; kb += 32) {
        GLD_LDS(gA + kb, lA);
        GLD_LDS(gB0 + kb, lB0);
        GLD_LDS(gB1 + kb, lB1);
        __syncthreads();

        bf16x8 af[2];
#pragma unroll
        for (int mt = 0; mt < 2; ++mt)
            af[mt] = *(const bf16x8*)&Ash[(wr * 32 + mt * 16 + l15) * 32 + quad * 8];
#pragma unroll
        for (int nt = 0; nt < 4; ++nt) {
            bf16x8 bh = *(const bf16x8*)&Bsh[(wc * 64 + nt * 16 + l15) * 32 + quad * 8];
#pragma unroll
            for (int mt = 0; mt < 2; ++mt)
                acc[mt][nt] = __builtin_amdgcn_mfma_f32_16x16x32_bf16(af[mt], bh, acc[mt][nt], 0, 0, 0);
        }
        __syncthreads();
    }

#pragma unroll
    for (int mt = 0; mt < 2; ++mt) {
#pragma unroll
        for (int nt = 0; nt < 4; ++nt) {
            const int gcol  = col0 + wc * 64 + nt * 16 + l15;
            const float bv  = bias[gcol];
            const int grow0 = row0 + wr * 32 + mt * 16 + quad * 4;
            if constexpr (MODE == 0) {
#pragma unroll
                for (int r = 0; r < 4; ++r)
                    outf[(long)(grow0 + r) * N + gcol] = acc[mt][nt][r] + bv;
            } else {
                const int hq = gcol >> 6, dk = gcol & 63;
                const int bq2 = grow0 >> 11;
                const int s0  = grow0 & (SS - 1);
                f16x4 pk;
#pragma unroll
                for (int r = 0; r < 4; ++r) pk[r] = (f16_t)(acc[mt][nt][r] + bv);
                *(f16x4*)(oh + ((long)(bq2 * HH + hq) * DKK + dk) * SS + s0) = pk;
            }
        }
    }
}

// ---------------------------------------------------------------- MFMA flash attention v2 (fp16, swizzled DMA staging)
__global__ __launch_bounds__(256) void attn_mfma2(const f16_t* __restrict__ Qp,
                                                  const f16_t* __restrict__ Kp,
                                                  const f16_t* __restrict__ Vtp,
                                                  const int* __restrict__ mask,
                                                  bf16_t* __restrict__ ctx,
                                                  int seq_len) {
    __shared__ __align__(16) f16_t Ksh[64 * 64];     // swizzled: col-group ^ (row&7)
    __shared__ __align__(16) f16_t Vsh[64 * 64];     // swizzled V^T tile [d][key]
    __shared__ __align__(16) f16_t Psh[4][16 * 68];  // stride 68: quad banks 0/8/16/24

    const int tid  = threadIdx.x;
    const int wv   = tid >> 6;
    const int lane = tid & 63;
    const int quad = lane >> 4;
    const int l15  = lane & 15;
    const int bh   = blockIdx.y;
    const int b    = bh >> 4;
    const int h    = bh & 15;
    const int q0   = blockIdx.x * 64 + wv * 16;

    const long kb = (long)bh * SS * DKK;  // same for Vt ([B,H,DK,S])

    // Q fragments (A-layout): A[m=q=l15][k=d=quad*8+j], d-tiles {0,32}
    f16x8 qf[2];
    {
        const f16_t* pq = Qp + kb + (long)(q0 + l15) * DKK + quad * 8;
        qf[0] = *(const f16x8*)pq;
        qf[1] = *(const f16x8*)(pq + 32);
    }

    f32x4 o[4];
    float m[4], l[4];
#pragma unroll
    for (int r = 0; r < 4; ++r) {
        o[r] = (f32x4){0.f, 0.f, 0.f, 0.f};
        m[r] = -1e30f;
        l[r] = 0.f;
    }

    const int* mrow = mask + b * SS;

    // DMA staging indices: inst i covers rows i*8..i*8+7; lane -> row i*8+(lane>>3),
    // stored col-group sg=lane&7 holds logical group g = sg ^ (row&7) = sg ^ (lane>>3)
    const int srow8 = lane >> 3;
    const int glg   = (lane & 7) ^ srow8;
    const int gcolB = glg * 8;

#pragma unroll 1
    for (int kt = 0; kt < seq_len; kt += 64) {
#pragma unroll
        for (int p = 0; p < 2; ++p) {
            const int i = wv * 2 + p;
            const int row = i * 8 + srow8;
            GLD_LDS(Kp + kb + (long)(kt + row) * DKK + gcolB, Ksh + i * 512);
            GLD_LDS(Vtp + kb + (long)row * SS + kt + gcolB, Vsh + i * 512);
        }
        __syncthreads();

        // ---- S = Q K^T (fp16 x1), D[m=q=quad*4+r][n=key=nt*16+l15]
        f32x4 s[4];
#pragma unroll
        for (int nt = 0; nt < 4; ++nt) s[nt] = (f32x4){0.f, 0.f, 0.f, 0.f};
#pragma unroll
        for (int nt = 0; nt < 4; ++nt) {
            const int kr = nt * 16 + l15;
#pragma unroll
            for (int dt = 0; dt < 2; ++dt) {
                f16x8 kf = *(const f16x8*)&Ksh[kr * 64 + (((dt * 4 + quad) ^ (l15 & 7)) << 3)];
                s[nt] = __builtin_amdgcn_mfma_f32_16x16x32_f16(qf[dt], kf, s[nt], 0, 0, 0);
            }
        }

        // ---- scale (x8) + key-padding mask
#pragma unroll
        for (int nt = 0; nt < 4; ++nt) {
            int keep = mrow[kt + nt * 16 + l15];
#pragma unroll
            for (int r = 0; r < 4; ++r)
                s[nt][r] = keep ? s[nt][r] * 8.0f : -1e30f;
        }

        // ---- row max over keys
        float tm[4];
#pragma unroll
        for (int r = 0; r < 4; ++r)
            tm[r] = fmaxf(fmaxf(s[0][r], s[1][r]), fmaxf(s[2][r], s[3][r]));
#pragma unroll
        for (int off = 1; off < 16; off <<= 1) {
#pragma unroll
            for (int r = 0; r < 4; ++r) tm[r] = fmaxf(tm[r], __shfl_xor(tm[r], off));
        }

        // ---- online softmax
        float alpha[4], ts[4];
#pragma unroll
        for (int r = 0; r < 4; ++r) {
            float mn = fmaxf(m[r], tm[r]);
            alpha[r] = __expf(m[r] - mn);
            m[r] = mn;
            ts[r] = 0.f;
        }
#pragma unroll
        for (int nt = 0; nt < 4; ++nt) {
#pragma unroll
            for (int r = 0; r < 4; ++r) {
                float p = __expf(s[nt][r] - m[r]);
                ts[r] += p;
                Psh[wv][(quad * 4 + r) * 68 + nt * 16 + l15] = (f16_t)p;
            }
        }
#pragma unroll
        for (int off = 1; off < 16; off <<= 1) {
#pragma unroll
            for (int r = 0; r < 4; ++r) ts[r] += __shfl_xor(ts[r], off);
        }
#pragma unroll
        for (int r = 0; r < 4; ++r) l[r] = l[r] * alpha[r] + ts[r];

#pragma unroll
        for (int t = 0; t < 4; ++t)
#pragma unroll
            for (int r = 0; r < 4; ++r) o[t][r] *= alpha[r];

        // ---- PV: A=P (per-wave LDS round-trip), B=V^T rows (swizzled)
#pragma unroll
        for (int kk = 0; kk < 2; ++kk) {
            f16x4 pa = *(const f16x4*)&Psh[wv][l15 * 68 + kk * 32 + quad * 8];
            f16x4 pb = *(const f16x4*)&Psh[wv][l15 * 68 + kk * 32 + quad * 8 + 4];
            f16x8 pf = __builtin_shufflevector(pa, pb, 0, 1, 2, 3, 4, 5, 6, 7);
#pragma unroll
            for (int t = 0; t < 4; ++t) {
                const int vr = t * 16 + l15;
                f16x8 vf = *(const f16x8*)&Vsh[vr * 64 + (((kk * 4 + quad) ^ (l15 & 7)) << 3)];
                o[t] = __builtin_amdgcn_mfma_f32_16x16x32_f16(pf, vf, o[t], 0, 0, 0);
            }
        }
        __syncthreads();
    }

    float inv[4];
#pragma unroll
    for (int r = 0; r < 4; ++r) inv[r] = 1.0f / l[r];
#pragma unroll
    for (int t = 0; t < 4; ++t) {
        int d = t * 16 + l15;
#pragma unroll
        for (int r = 0; r < 4; ++r) {
            int tok = b * SS + q0 + quad * 4 + r;
            ctx[(long)tok * DD + h * DKK + d] = (bf16_t)(o[t][r] * inv[r]);
        }
    }
}

// ---------------------------------------------------------------- launch
extern "C" void kernel_launch(void* const* d_in, const int* in_sizes, int n_in,
                              void* d_out, int out_size, void* d_ws, size_t ws_size,
                              hipStream_t stream) {
    const float* x  = (const float*)d_in[0];
    const int* mask = (const int*)d_in[1];
    const float* Wq = (const float*)d_in[2];
    const float* bq = (const float*)d_in[3];
    const float* Wk = (const float*)d_in[4];
    const float* bk = (const float*)d_in[5];
    const float* Wv = (const float*)d_in[6];
    const float* bv = (const float*)d_in[7];
    const float* Wo = (const float*)d_in[8];
    const float* bo = (const float*)d_in[9];
    float* out = (float*)d_out;

    const long NX = (long)BB * SS * DD;  // 4194304
    const long NW = (long)DD * DD;       // 1048576

    char* ws = (char*)d_ws;
    bf16_t* xh   = (bf16_t*)ws; ws += NX * 2;
    bf16_t* xl   = (bf16_t*)ws; ws += NX * 2;
    bf16_t* wqkh = (bf16_t*)ws; ws += 2 * NW * 2;
    bf16_t* wqkl = (bf16_t*)ws; ws += 2 * NW * 2;
    bf16_t* wvb  = (bf16_t*)ws; ws += NW * 2;
    bf16_t* wob  = (bf16_t*)ws; ws += NW * 2;
    f16_t*  qf   = (f16_t*)ws;  ws += NX * 2;
    f16_t*  kf   = (f16_t*)ws;  ws += NX * 2;
    f16_t*  vt   = (f16_t*)ws;  ws += NX * 2;
    bf16_t* ctx  = (bf16_t*)ws; ws += NX * 2;

    cast_split<<<2048, 256, 0, stream>>>(x, xh, xl, (int)NX);
    cast_split<<<512, 256, 0, stream>>>(Wq, wqkh, wqkl, (int)NW);
    cast_split<<<512, 256, 0, stream>>>(Wk, wqkh + NW, wqkl + NW, (int)NW);
    cast_f32_bf16<<<512, 256, 0, stream>>>(Wv, wvb, (int)NW);
    cast_f32_bf16<<<512, 256, 0, stream>>>(Wo, wob, (int)NW);

    dim3 gqk(2 * DD / 128, (BB * SS) / 128);  // (16, 32) = 512 blocks
    gemm_qk<<<gqk, 256, 0, stream>>>(xh, xl, wqkh, wqkl, bq, bk, qf, kf, DD);

    dim3 g2(DD / 128, (BB * SS) / 64);  // (8, 64) = 512 blocks
    gemm2<2><<<g2, 256, 0, stream>>>(xh, wvb, bv, nullptr, vt, DD, DD);

    dim3 agrid(SS / 64, BB * HH);  // (32, 32)
    attn_mfma2<<<agrid, 256, 0, stream>>>(qf, kf, vt, mask, ctx, SS);

    gemm2<0><<<g2, 256, 0, stream>>>(ctx, wob, bo, out, nullptr, DD, DD);
}